// Round 3
// baseline (1041.283 us; speedup 1.0000x reference)
//
#include <hip/hip_runtime.h>
#include <cstdint>
#include <cstddef>

#define NB 8
#define NPTS 8192
#define S_TOT 512
#define NSAMP 64
#define DFEAT 64
#define INCH 67
#define CCAP 8448   // per-(b,grp) compacted capacity

// exact (numpy-matching) squared distance: (a-b) per component, square, sum as (x+y)+z
__device__ __forceinline__ float d2_exact(float ax, float ay, float az,
                                          float bx, float by, float bz) {
    float dx = __fsub_rn(ax, bx);
    float dy = __fsub_rn(ay, by);
    float dz = __fsub_rn(az, bz);
    return __fadd_rn(__fadd_rn(__fmul_rn(dx, dx), __fmul_rn(dy, dy)), __fmul_rn(dz, dz));
}

// ---------------------------------------------------------------------------
// FPS stage 1: compaction. attention is a 0/1 mask, so masked-out points are
// all exactly (+/-0,+/-0,+/-0): bit-identical min_d2 trajectory (squaring kills
// zero signs). Collapse them to ONE representative with the MIN original index
// — exact under numpy first-occurrence argmax since every comparison below
// tie-breaks on original index. Kept points have f==1 -> coords unchanged.
// grid 16 = (b,grp); 1024 threads, 8 contiguous points each; prefix-scan write.
// ---------------------------------------------------------------------------
__global__ __launch_bounds__(1024) void fps_compact(
    const float* __restrict__ xyz, const float* __restrict__ attn,
    float* __restrict__ cx, float* __restrict__ cy, float* __restrict__ cz,
    int* __restrict__ ci, int* __restrict__ hdr)
{
    int blk = blockIdx.x;
    int b = blk >> 1, grp = blk & 1;
    const float* xb = xyz + (size_t)b * 3 * NPTS;
    const float* ab = attn + (size_t)b * NPTS;
    cx += blk * CCAP; cy += blk * CCAP; cz += blk * CCAP; ci += blk * CCAP;

    int tid = threadIdx.x, lane = tid & 63, wid = tid >> 6;
    int n0 = tid * 8;

    __shared__ int s_repmin;
    __shared__ int s_ws[16];
    if (tid == 0) s_repmin = NPTS;
    __syncthreads();

    float av[8];
    *(float4*)&av[0] = *(const float4*)(ab + n0);
    *(float4*)&av[4] = *(const float4*)(ab + n0 + 4);
    int cnt = 0, mymin = NPTS;
    bool keep[8];
#pragma unroll
    for (int j = 0; j < 8; j++) {
        keep[j] = grp ? (av[j] == 0.0f) : (av[j] != 0.0f);
        cnt += keep[j] ? 1 : 0;
        if (!keep[j] && n0 + j < mymin) mymin = n0 + j;
    }
    if (mymin < NPTS) atomicMin(&s_repmin, mymin);

    int incl = cnt;
#pragma unroll
    for (int off = 1; off <= 32; off <<= 1) {
        int t = __shfl_up(incl, off);
        if (lane >= off) incl += t;
    }
    if (lane == 63) s_ws[wid] = incl;
    __syncthreads();
    int woff = 0, tot = 0;
#pragma unroll
    for (int w = 0; w < 16; w++) { if (w < wid) woff += s_ws[w]; tot += s_ws[w]; }
    int pos = woff + incl - cnt;

    float xv[8], yv[8], zv[8];
    *(float4*)&xv[0] = *(const float4*)(xb + n0);
    *(float4*)&xv[4] = *(const float4*)(xb + n0 + 4);
    *(float4*)&yv[0] = *(const float4*)(xb + NPTS + n0);
    *(float4*)&yv[4] = *(const float4*)(xb + NPTS + n0 + 4);
    *(float4*)&zv[0] = *(const float4*)(xb + 2 * NPTS + n0);
    *(float4*)&zv[4] = *(const float4*)(xb + 2 * NPTS + n0 + 4);
#pragma unroll
    for (int j = 0; j < 8; j++) {
        if (keep[j]) { cx[pos] = xv[j]; cy[pos] = yv[j]; cz[pos] = zv[j]; ci[pos] = n0 + j; pos++; }
    }
    if (tid == 0) {
        int M = tot, rm = s_repmin;
        if (rm < NPTS) {   // representative: signed zeros like f*x for exactness of out0
            cx[M] = __fmul_rn(0.0f, xb[rm]);
            cy[M] = __fmul_rn(0.0f, xb[NPTS + rm]);
            cz[M] = __fmul_rn(0.0f, xb[2 * NPTS + rm]);
            ci[M] = rm; M++;
        }
        hdr[blk * 2] = M;
        hdr[blk * 2 + 1] = (rm < NPTS) ? rm : -1;
    }
}

// ---------------------------------------------------------------------------
// FPS stage 2: the serial chain. 256 threads (1 wave/SIMD, up to 512 VGPR ->
// slot arrays never spill). Explicit (md, idx) lexicographic compare at every
// level = numpy argmax first-occurrence regardless of slot order. Winner
// coords routed through LDS (not an L2 reload).
// ---------------------------------------------------------------------------
template <int S>
__device__ __forceinline__ void fps_core(
    const float* __restrict__ cx, const float* __restrict__ cy,
    const float* __restrict__ cz, const int* __restrict__ ci,
    int M, int repmin, int grp, int K, int soff, int b,
    const float* __restrict__ xb, const float* __restrict__ ab,
    float* __restrict__ out0, float* __restrict__ out2)
{
    int tid = threadIdx.x, lane = tid & 63, wid = tid >> 6;

    float px[S], py[S], pz[S], md[S];
    int ix[S];
#pragma unroll
    for (int i = 0; i < S; i++) {
        int sl = i * 256 + tid;
        bool v = sl < M;
        px[i] = v ? cx[sl] : 0.0f;
        py[i] = v ? cy[sl] : 0.0f;
        pz[i] = v ? cz[sl] : 0.0f;
        ix[i] = v ? ci[sl] : 0x7fffffff;
        md[i] = v ? 1e10f : -1.0f;      // invalid: stays -1 (fminf with d2>=0), never wins
    }

    float a0 = ab[0];
    float f0 = grp ? __fsub_rn(1.0f, a0) : a0;
    float lx = __fmul_rn(f0, xb[0]);
    float ly = __fmul_rn(f0, xb[NPTS]);
    float lz = __fmul_rn(f0, xb[2 * NPTS]);
    float a_last = a0;
    float kept_a = grp ? 0.0f : 1.0f;
    float rep_a  = grp ? 1.0f : 0.0f;

    __shared__ unsigned long long s_wk[2][4];
    __shared__ float s_wx[2][4], s_wy[2][4], s_wz[2][4];

    for (int k = 0; k < K; k++) {
        if (tid == 0) {
            int sg = soff + k;
            out0[(size_t)b * 3 * S_TOT + sg] = lx;
            out0[(size_t)b * 3 * S_TOT + S_TOT + sg] = ly;
            out0[(size_t)b * 3 * S_TOT + 2 * S_TOT + sg] = lz;
            out2[(size_t)b * S_TOT + sg] = a_last;
        }
        if (k == K - 1) break;

        float bv = -2.0f; int bi = 0x7fffffff;
        float bx = 0.f, by = 0.f, bz = 0.f;
#pragma unroll
        for (int i = 0; i < S; i++) {
            float d2 = d2_exact(px[i], py[i], pz[i], lx, ly, lz);
            md[i] = fminf(md[i], d2);
            bool w = (md[i] > bv) || (md[i] == bv && ix[i] < bi);
            if (w) { bv = md[i]; bi = ix[i]; bx = px[i]; by = py[i]; bz = pz[i]; }
        }
        unsigned long long key = (bv >= 0.0f)
            ? (((unsigned long long)__float_as_uint(bv) << 32) | (unsigned)(~bi))
            : 0ull;
        unsigned long long rk = key;
#pragma unroll
        for (int off = 32; off >= 1; off >>= 1) {
            unsigned long long o = __shfl_down(rk, off);
            rk = (o > rk) ? o : rk;
        }
        unsigned long long wk = __shfl(rk, 0);
        int buf = k & 1;
        if (key == wk && wk != 0ull) { s_wx[buf][wid] = bx; s_wy[buf][wid] = by; s_wz[buf][wid] = bz; }
        if (lane == 0) s_wk[buf][wid] = rk;
        __syncthreads();

        unsigned long long mine = (lane < 4) ? s_wk[buf][lane] : 0ull;
        unsigned long long rr = mine;
#pragma unroll
        for (int off = 2; off >= 1; off >>= 1) {
            unsigned long long o = __shfl_down(rr, off);
            rr = (o > rr) ? o : rr;
        }
        unsigned long long g = __shfl(rr, 0);
        unsigned long long bal = __ballot(lane < 4 && mine == g && g != 0ull);
        int ww = bal ? (__ffsll((long long)bal) - 1) : 0;
        lx = s_wx[buf][ww]; ly = s_wy[buf][ww]; lz = s_wz[buf][ww];
        int n = (int)(~(unsigned)g);
        a_last = (n == repmin) ? rep_a : kept_a;
    }
}

__global__ __launch_bounds__(256, 1) void fps_iter(
    const float* __restrict__ xyz, const float* __restrict__ attn,
    const float* __restrict__ cx, const float* __restrict__ cy,
    const float* __restrict__ cz, const int* __restrict__ ci,
    const int* __restrict__ hdr,
    float* __restrict__ out0, float* __restrict__ out2)
{
    int blk = blockIdx.x;
    int b = blk >> 1, grp = blk & 1;
    int K = grp ? 384 : 128;
    int soff = grp ? 128 : 0;
    const float* xb = xyz + (size_t)b * 3 * NPTS;
    const float* ab = attn + (size_t)b * NPTS;
    int M = hdr[blk * 2];
    int repmin = hdr[blk * 2 + 1];
    const float* rcx = cx + blk * CCAP;
    const float* rcy = cy + blk * CCAP;
    const float* rcz = cz + blk * CCAP;
    const int*   rci = ci + blk * CCAP;
    if (M <= 17 * 256)
        fps_core<17>(rcx, rcy, rcz, rci, M, repmin, grp, K, soff, b, xb, ab, out0, out2);
    else
        fps_core<33>(rcx, rcy, rcz, rci, M, repmin, grp, K, soff, b, xb, ab, out0, out2);
}

// ---------------------------------------------------------------------------
// Fallback FPS (R2 version) if ws is too small for compaction arrays.
// ---------------------------------------------------------------------------
__global__ __launch_bounds__(1024, 1) void fps_kernel(
    const float* __restrict__ xyz, const float* __restrict__ attn,
    float* __restrict__ out0, float* __restrict__ out2)
{
    int blk = blockIdx.x;
    int b = blk >> 1, grp = blk & 1;
    int K = grp ? 384 : 128;
    int soff = grp ? 128 : 0;
    int tid = threadIdx.x, lane = tid & 63, wid = tid >> 6;
    const float* xb = xyz + (size_t)b * 3 * NPTS;
    const float* ab = attn + (size_t)b * NPTS;

    float px[8], py[8], pz[8], md[8];
#pragma unroll
    for (int i = 0; i < 8; i++) {
        int n = tid + i * 1024;
        float a = ab[n];
        float f = grp ? __fsub_rn(1.0f, a) : a;
        px[i] = __fmul_rn(f, xb[n]);
        py[i] = __fmul_rn(f, xb[NPTS + n]);
        pz[i] = __fmul_rn(f, xb[2 * NPTS + n]);
        md[i] = 1e10f;
    }
    __shared__ unsigned long long s_red[2][16];
    float a_last = ab[0];
    float f0 = grp ? __fsub_rn(1.0f, a_last) : a_last;
    float lx = __fmul_rn(f0, xb[0]);
    float ly = __fmul_rn(f0, xb[NPTS]);
    float lz = __fmul_rn(f0, xb[2 * NPTS]);

    for (int k = 0; k < K; k++) {
        if (tid == 0) {
            int sg = soff + k;
            out0[(size_t)b * 3 * S_TOT + sg] = lx;
            out0[(size_t)b * 3 * S_TOT + S_TOT + sg] = ly;
            out0[(size_t)b * 3 * S_TOT + 2 * S_TOT + sg] = lz;
            out2[(size_t)b * S_TOT + sg] = a_last;
        }
        if (k == K - 1) break;
        float bv = -1.0f; int bi = 0;
#pragma unroll
        for (int i = 0; i < 8; i++) {
            float d2 = d2_exact(px[i], py[i], pz[i], lx, ly, lz);
            md[i] = fminf(md[i], d2);
            if (md[i] > bv) { bv = md[i]; bi = tid + i * 1024; }
        }
        unsigned long long best =
            ((unsigned long long)__float_as_uint(bv) << 32) | (unsigned)(~bi);
#pragma unroll
        for (int off = 32; off >= 1; off >>= 1) {
            unsigned long long o = __shfl_down(best, off);
            best = (o > best) ? o : best;
        }
        if (lane == 0) s_red[k & 1][wid] = best;
        __syncthreads();
        unsigned long long r = (lane < 16) ? s_red[k & 1][lane] : 0ull;
#pragma unroll
        for (int off = 8; off >= 1; off >>= 1) {
            unsigned long long o = __shfl_down(r, off);
            r = (o > r) ? o : r;
        }
        r = __shfl(r, 0);
        int n = (int)(~(unsigned)r);
        a_last = ab[n];
        float fl = grp ? __fsub_rn(1.0f, a_last) : a_last;
        lx = __fmul_rn(fl, xb[n]);
        ly = __fmul_rn(fl, xb[NPTS + n]);
        lz = __fmul_rn(fl, xb[2 * NPTS + n]);
    }
}

// ---------------------------------------------------------------------------
// points [B,64,N] -> ptsT [B,N,64], tiled 64x64 via LDS
// ---------------------------------------------------------------------------
__global__ void transpose_pts(const float* __restrict__ pts, float* __restrict__ ptsT) {
    __shared__ float t[64][65];
    int b = blockIdx.y;
    int n0 = blockIdx.x * 64;
    int tx = threadIdx.x, ty = threadIdx.y;
    for (int c = ty; c < 64; c += 4)
        t[c][tx] = pts[((size_t)b * DFEAT + c) * NPTS + n0 + tx];
    __syncthreads();
    for (int r = ty; r < 64; r += 4)
        ptsT[((size_t)b * NPTS + n0 + r) * DFEAT + tx] = t[tx][r];
}

// w0 [64][67] -> w0T [67][64]; w1 [64][64] -> w1T [64][64]
__global__ void transpose_w(const float* __restrict__ w0, const float* __restrict__ w1,
                            float* __restrict__ w0T, float* __restrict__ w1T) {
    int t = blockIdx.x * 256 + threadIdx.x;
    if (t < INCH * 64) { int o = t & 63, c = t >> 6; w0T[c * 64 + o] = w0[o * INCH + c]; }
    if (t < 64 * 64)   { int o = t & 63, c = t >> 6; w1T[c * 64 + o] = w1[o * 64 + c]; }
}

// ---------------------------------------------------------------------------
// Ball query + feature build + 3-layer MLP + max over 64 samples.
// One wave per query. Ball scan has NO early exit: all 384 chunk loads are
// independent -> fully pipelined (the R2 exit branch made each chunk's loads
// wait on the previous ballot -> ~128 serialized L2 latencies for far queries).
// ---------------------------------------------------------------------------
__global__ __launch_bounds__(64, 2) void ball_mlp(
    const float* __restrict__ xyz,
    const float* __restrict__ pts,
    const float* __restrict__ ptsT,
    int use_ptsT,
    const float* __restrict__ w0T, const float* __restrict__ w1T, int use_wT,
    const float* __restrict__ w0, const float* __restrict__ b0,
    const float* __restrict__ w1, const float* __restrict__ b1,
    const float* __restrict__ w2, const float* __restrict__ b2,
    const float* __restrict__ out0,
    float* __restrict__ out1)
{
    const float R2 = (float)(0.4 * 0.4);   // 0x3E23D70A — NOT 0.4f*0.4f
    int q = blockIdx.x;
    int b = q >> 9;
    int sg = q & 511;
    int lane = threadIdx.x;

    const float* xb = xyz + (size_t)b * 3 * NPTS;
    float qx = out0[(size_t)b * 3 * S_TOT + sg];
    float qy = out0[(size_t)b * 3 * S_TOT + S_TOT + sg];
    float qz = out0[(size_t)b * 3 * S_TOT + 2 * S_TOT + sg];

    __shared__ int s_idx[NSAMP];
    int cnt = 0;
#pragma unroll 4
    for (int base = 0; base < NPTS; base += 64) {
        int n = base + lane;
        float d2 = d2_exact(qx, qy, qz, xb[n], xb[NPTS + n], xb[2 * NPTS + n]);
        bool flag = d2 < R2;
        unsigned long long m = __ballot(flag);
        int pos = cnt + (int)__popcll(m & ((1ull << lane) - 1ull));
        if (flag && pos < NSAMP) s_idx[pos] = n;
        cnt += (int)__popcll(m);
    }
    __syncthreads();
    if (cnt > NSAMP) cnt = NSAMP;

    int nb = (lane < cnt) ? s_idx[lane] : -1;
    float nx_ = 0.f, ny_ = 0.f, nz_ = 0.f;
    if (nb >= 0) { nx_ = xb[nb]; ny_ = xb[NPTS + nb]; nz_ = xb[2 * NPTS + nb]; }
    float fx = nx_ - qx, fy = ny_ - qy, fz = nz_ - qz;   // pad: -new_xyz (ref semantics)
    int row = (nb < 0) ? (NPTS - 1) : nb;                // torch -1 wraps to last point

    // ---- layer 1: 67 -> 64 ----
    float h1[64];
    if (use_wT) {
#pragma unroll
        for (int o = 0; o < 64; o++) {
            float a = __builtin_fmaf(w0T[o], fx, b0[o]);
            a = __builtin_fmaf(w0T[64 + o], fy, a);
            h1[o] = __builtin_fmaf(w0T[128 + o], fz, a);
        }
        if (use_ptsT) {
            const float* prow = ptsT + ((size_t)b * NPTS + row) * DFEAT;
#pragma unroll 1
            for (int c = 0; c < 64; c += 4) {
                float4 f4 = *(const float4*)(prow + c);
                const float* wr = w0T + (3 + c) * 64;
#pragma unroll
                for (int o = 0; o < 64; o++) {
                    float a = __builtin_fmaf(wr[o], f4.x, h1[o]);
                    a = __builtin_fmaf(wr[64 + o], f4.y, a);
                    a = __builtin_fmaf(wr[128 + o], f4.z, a);
                    h1[o] = __builtin_fmaf(wr[192 + o], f4.w, a);
                }
            }
        } else {
            const float* pb = pts + (size_t)b * DFEAT * NPTS + row;
#pragma unroll 1
            for (int c = 0; c < 64; c++) {
                float f = pb[(size_t)c * NPTS];
                const float* wr = w0T + (3 + c) * 64;
#pragma unroll
                for (int o = 0; o < 64; o++)
                    h1[o] = __builtin_fmaf(wr[o], f, h1[o]);
            }
        }
    } else {
#pragma unroll
        for (int o = 0; o < 64; o++) {
            float a = __builtin_fmaf(w0[o * INCH + 0], fx, b0[o]);
            a = __builtin_fmaf(w0[o * INCH + 1], fy, a);
            h1[o] = __builtin_fmaf(w0[o * INCH + 2], fz, a);
        }
        const float* pb = pts + (size_t)b * DFEAT * NPTS + row;
#pragma unroll 1
        for (int c = 0; c < 64; c++) {
            float f = use_ptsT ? ptsT[((size_t)b * NPTS + row) * DFEAT + c]
                               : pb[(size_t)c * NPTS];
#pragma unroll
            for (int o = 0; o < 64; o++)
                h1[o] = __builtin_fmaf(w0[o * INCH + 3 + c], f, h1[o]);
        }
    }
#pragma unroll
    for (int o = 0; o < 64; o++) h1[o] = fmaxf(h1[o], 0.0f);

    // ---- layer 2: 64 -> 64 ----
    float h2[64];
#pragma unroll
    for (int o = 0; o < 64; o++) h2[o] = b1[o];
    if (use_wT) {
#pragma unroll
        for (int c = 0; c < 64; c++) {
            float hc = h1[c];
            const float* wr = w1T + c * 64;
#pragma unroll
            for (int o = 0; o < 64; o++)
                h2[o] = __builtin_fmaf(wr[o], hc, h2[o]);
        }
    } else {
#pragma unroll
        for (int c = 0; c < 64; c++) {
            float hc = h1[c];
#pragma unroll
            for (int o = 0; o < 64; o++)
                h2[o] = __builtin_fmaf(w1[o * 64 + c], hc, h2[o]);
        }
    }
#pragma unroll
    for (int o = 0; o < 64; o++) h2[o] = fmaxf(h2[o], 0.0f);

    // ---- layer 3: 64 -> 128, relu, lane-max ----
#pragma unroll 2
    for (int o = 0; o < 128; o++) {
        const float* wr = w2 + o * 64;
        float acc = b2[o];
#pragma unroll
        for (int c = 0; c < 64; c++) acc = __builtin_fmaf(wr[c], h2[c], acc);
        acc = fmaxf(acc, 0.0f);   // relu(max) == max(relu): monotone
#pragma unroll
        for (int off = 32; off >= 1; off >>= 1)
            acc = fmaxf(acc, __shfl_down(acc, off));
        if (lane == 0) out1[((size_t)(b * 128 + o)) * S_TOT + sg] = acc;
    }
}

extern "C" void kernel_launch(void* const* d_in, const int* in_sizes, int n_in,
                              void* d_out, int out_size, void* d_ws, size_t ws_size,
                              hipStream_t stream) {
    const float* xyz  = (const float*)d_in[0];
    const float* pts  = (const float*)d_in[1];
    const float* attn = (const float*)d_in[2];
    const float* w0 = (const float*)d_in[3];
    const float* b0 = (const float*)d_in[4];
    const float* w1 = (const float*)d_in[5];
    const float* b1 = (const float*)d_in[6];
    const float* w2 = (const float*)d_in[7];
    const float* b2 = (const float*)d_in[8];

    float* out0 = (float*)d_out;                    // [B,3,S]   = 12288
    float* out1 = out0 + (size_t)NB * 3 * S_TOT;    // [B,128,S] = 524288
    float* out2 = out1 + (size_t)NB * 128 * S_TOT;  // [B,1,S]   = 4096

    // ws layout (floats): w0T(4288) w1T(4096) pad->8448 | ptsT 4194304 |
    //   cx[16*8448] cy cz ci | hdr(32 ints)
    float* w0T  = (float*)d_ws;
    float* w1T  = w0T + INCH * 64;
    float* ptsT = w0T + 8448;
    float* cx   = ptsT + (size_t)NB * NPTS * DFEAT;
    float* cy   = cx + 16 * CCAP;
    float* cz   = cy + 16 * CCAP;
    int*   cidx = (int*)(cz + 16 * CCAP);
    int*   hdr  = cidx + 16 * CCAP;

    const size_t wT_f    = 8448;
    const size_t ptsT_f  = (size_t)NB * NPTS * DFEAT;
    const size_t full_f  = wT_f + ptsT_f + (size_t)4 * 16 * CCAP + 32;
    int use_wT   = (ws_size >= wT_f * 4) ? 1 : 0;
    int use_ptsT = (ws_size >= (wT_f + ptsT_f) * 4) ? 1 : 0;
    int use_fps2 = (ws_size >= full_f * 4) ? 1 : 0;

    if (use_wT)
        transpose_w<<<(INCH * 64 + 255) / 256, 256, 0, stream>>>(w0, w1, w0T, w1T);
    if (use_ptsT)
        transpose_pts<<<dim3(NPTS / 64, NB), dim3(64, 4), 0, stream>>>(pts, ptsT);
    if (use_fps2) {
        fps_compact<<<16, 1024, 0, stream>>>(xyz, attn, cx, cy, cz, cidx, hdr);
        fps_iter<<<16, 256, 0, stream>>>(xyz, attn, cx, cy, cz, cidx, hdr, out0, out2);
    } else {
        fps_kernel<<<16, 1024, 0, stream>>>(xyz, attn, out0, out2);
    }
    ball_mlp<<<NB * S_TOT, 64, 0, stream>>>(xyz, pts, ptsT, use_ptsT,
                                            w0T, w1T, use_wT,
                                            w0, b0, w1, b1, w2, b2, out0, out1);
}